// Round 7
// baseline (1095.509 us; speedup 1.0000x reference)
//
#include <hip/hip_runtime.h>
#include <hip/hip_bf16.h>

#define NN 50000
#define EE 800000
#define GG 64
#define LL 3
#define CC 4
#define HH 64
#define BN_EPS 1e-5f
#define NSHADOW 16
#define SBLK 196          // ceil(NN/256) node-parallel blocks
#define GIN_BLOCKS 800    // 4 waves/block * 4 nodes/wave = 16 nodes/block

// NOTE: harness passes ALL integer inputs as int32 (edge_index/batch included).
// NOTE: cooperative launch + grid.sync measured 4x SLOWER than kernel-boundary
//       barriers on this problem (R5: 5154us vs 1230us) — do not reintroduce.
// NOTE: single-block k_final measured 90us (latency-bound) — keep final MLP split.

// ---------------- setup kernels ----------------

__global__ void k_deghist(const int* __restrict__ dst, int* __restrict__ deg,
                          const int* __restrict__ labels, int* __restrict__ blockcnt) {
    __shared__ int cnt[CC];
    int tid = threadIdx.x;
    bool hist = (blockIdx.x < SBLK);
    if (hist && tid < CC) cnt[tid] = 0;
    __syncthreads();
    int gid = blockIdx.x * 256 + tid;
    if (gid < EE) atomicAdd(&deg[dst[gid]], 1);
    if (hist && gid < NN) atomicAdd(&cnt[labels[gid]], 1);
    __syncthreads();
    if (hist && tid < CC) blockcnt[tid * SBLK + blockIdx.x] = cnt[tid];
}

__global__ __launch_bounds__(256) void k_scancombo(
    const int* __restrict__ deg, int* __restrict__ rowptr, int* __restrict__ dpart,
    const int* __restrict__ blockcnt, int* __restrict__ coffs, int* __restrict__ ccount) {
    __shared__ int smem[CC * 256];
    int tid = threadIdx.x;
    if (blockIdx.x < SBLK) {
        int i = blockIdx.x * 256 + tid;
        int v = (i < NN) ? deg[i] : 0;
        smem[tid] = v;
        __syncthreads();
        for (int off = 1; off < 256; off <<= 1) {
            int u = (tid >= off) ? smem[tid - off] : 0;
            __syncthreads();
            smem[tid] += u;
            __syncthreads();
        }
        if (i < NN) rowptr[i] = smem[tid] - v;  // local exclusive
        if (tid == 255) dpart[blockIdx.x] = smem[255];
    } else {
        int own[CC];
        for (int c = 0; c < CC; c++) {
            own[c] = (tid < SBLK) ? blockcnt[c * SBLK + tid] : 0;
            smem[c * 256 + tid] = own[c];
        }
        __syncthreads();
        for (int off = 1; off < 256; off <<= 1) {
            int v[CC];
            for (int c = 0; c < CC; c++) v[c] = (tid >= off) ? smem[c * 256 + tid - off] : 0;
            __syncthreads();
            for (int c = 0; c < CC; c++) smem[c * 256 + tid] += v[c];
            __syncthreads();
        }
        if (tid < SBLK)
            for (int c = 0; c < CC; c++) coffs[c * SBLK + tid] = smem[c * 256 + tid] - own[c];
        if (tid == 0)
            for (int c = 0; c < CC; c++) ccount[c] = smem[c * 256 + 255];
    }
}

__global__ __launch_bounds__(256) void k_dscan2(int* __restrict__ dpart,
                                                int* __restrict__ dbase,
                                                int* __restrict__ rowptr) {
    __shared__ int s[256];
    int tid = threadIdx.x;
    int v = (tid < SBLK) ? dpart[tid] : 0;
    s[tid] = v;
    __syncthreads();
    for (int off = 1; off < 256; off <<= 1) {
        int u = (tid >= off) ? s[tid - off] : 0;
        __syncthreads();
        s[tid] += u;
        __syncthreads();
    }
    if (tid < SBLK) dbase[tid] = s[tid] - v;
    if (tid == 0) rowptr[NN] = EE;
}

__global__ __launch_bounds__(256) void k_cfill_dscan3(
    int* __restrict__ rowptr, const int* __restrict__ dbase, int* __restrict__ cursor,
    const int* __restrict__ labels, const int* __restrict__ coffs, int* __restrict__ clist) {
    __shared__ int pos[CC];
    int tid = threadIdx.x;
    if (tid < CC) pos[tid] = coffs[tid * SBLK + blockIdx.x];
    __syncthreads();
    int i = blockIdx.x * 256 + tid;
    if (i < NN) {
        int r = rowptr[i] + dbase[blockIdx.x];
        rowptr[i] = r;
        cursor[i] = r;
        int c = labels[i];
        int p = atomicAdd(&pos[c], 1);
        clist[c * NN + p] = i;
    }
}

__global__ void k_fill(const int* __restrict__ src, const int* __restrict__ dst,
                       int* __restrict__ cursor, int* __restrict__ adj) {
    int e = blockIdx.x * blockDim.x + threadIdx.x;
    if (e < EE) {
        int d = dst[e];
        int pos = atomicAdd(&cursor[d], 1);
        adj[pos] = src[e];
    }
}

// ---------------- per-(t,c) kernels ----------------
// Layout: 16 lanes (li) x float4 hold one node row; sub = lane>>4 selects one of
// 4 nodes per wave. Channel 4*li+m lives in component m of lane li.

// Kernel A: agg (CSR gather, 8 indep float4 chains/node) + h1 = (agg+x)@W1 + b1; BN partials.
__global__ __launch_bounds__(256) void k_gin_a(
    const float* __restrict__ xw, const int* __restrict__ adj,
    const int* __restrict__ rowptr, const int* __restrict__ clist_c,
    const int* __restrict__ ccount_c, const float* __restrict__ W1,
    const float* __restrict__ b1, float* __restrict__ h1buf,
    float* __restrict__ bnacc) {
    __shared__ float lds_red[4][128];
    const int cnt = *ccount_c;
    const int lane = threadIdx.x & 63;
    const int wave = threadIdx.x >> 6;
    const int li = lane & 15;
    const int sub = lane >> 4;
    const int wid = blockIdx.x * 4 + wave;
    const int nwaves = gridDim.x * 4;
    const float4* __restrict__ xw4 = (const float4*)xw;
    const float4* __restrict__ W14 = (const float4*)W1;
    const float4* __restrict__ b14 = (const float4*)b1;
    float4* __restrict__ h1buf4 = (float4*)h1buf;

    float4 sS = make_float4(0.f, 0.f, 0.f, 0.f);
    float4 sQ = make_float4(0.f, 0.f, 0.f, 0.f);

    for (int g0 = wid * 4; g0 < cnt; g0 += nwaves * 4) {
        int idx = g0 + sub;
        bool active = (idx < cnt);
        int node = clist_c[active ? idx : 0];
        int rb = rowptr[node], re = rowptr[node + 1];
        float4 acc[8];
        #pragma unroll
        for (int u = 1; u < 8; u++) acc[u] = make_float4(0.f, 0.f, 0.f, 0.f);
        acc[0] = xw4[node * 16 + li];  // self row: h = agg + x
        int base = rb, rem = re - rb;
        while (rem > 0) {
            int take = min(rem, 16);
            int nb = adj[base + min(li, take - 1)];  // 16-lane coalesced
            for (int j = 0; j < take; j += 8) {
                #pragma unroll
                for (int u = 0; u < 8; u++) {
                    int jj = j + u;
                    int n = __shfl(nb, sub * 16 + (jj < take ? jj : 0));
                    if (jj < take) {
                        float4 v = xw4[n * 16 + li];
                        acc[u].x += v.x; acc[u].y += v.y; acc[u].z += v.z; acc[u].w += v.w;
                    }
                }
            }
            base += take; rem -= take;
        }
        float4 h;
        h.x = ((acc[0].x + acc[1].x) + (acc[2].x + acc[3].x)) +
              ((acc[4].x + acc[5].x) + (acc[6].x + acc[7].x));
        h.y = ((acc[0].y + acc[1].y) + (acc[2].y + acc[3].y)) +
              ((acc[4].y + acc[5].y) + (acc[6].y + acc[7].y));
        h.z = ((acc[0].z + acc[1].z) + (acc[2].z + acc[3].z)) +
              ((acc[4].z + acc[5].z) + (acc[6].z + acc[7].z));
        h.w = ((acc[0].w + acc[1].w) + (acc[2].w + acc[3].w)) +
              ((acc[4].w + acc[5].w) + (acc[6].w + acc[7].w));
        // Lin1: outputs 4*li+m in s.m ; h[4k+u] = comp u of lane sub*16+k
        float4 s = b14[li];
        #pragma unroll
        for (int k = 0; k < 16; k++) {
            float h0 = __shfl(h.x, sub * 16 + k);
            float h1v = __shfl(h.y, sub * 16 + k);
            float h2 = __shfl(h.z, sub * 16 + k);
            float h3 = __shfl(h.w, sub * 16 + k);
            float4 w0 = W14[(4 * k + 0) * 16 + li];
            float4 w1 = W14[(4 * k + 1) * 16 + li];
            float4 w2 = W14[(4 * k + 2) * 16 + li];
            float4 w3 = W14[(4 * k + 3) * 16 + li];
            s.x += h0 * w0.x + h1v * w1.x + h2 * w2.x + h3 * w3.x;
            s.y += h0 * w0.y + h1v * w1.y + h2 * w2.y + h3 * w3.y;
            s.z += h0 * w0.z + h1v * w1.z + h2 * w2.z + h3 * w3.z;
            s.w += h0 * w0.w + h1v * w1.w + h2 * w2.w + h3 * w3.w;
        }
        if (active) {
            h1buf4[(size_t)idx * 16 + li] = s;
            sS.x += s.x; sS.y += s.y; sS.z += s.z; sS.w += s.w;
            sQ.x += s.x * s.x; sQ.y += s.y * s.y; sQ.z += s.z * s.z; sQ.w += s.w * s.w;
        }
    }
    // cross-sub reduce (channels replicated in lanes li, li+16, li+32, li+48)
    sS.x += __shfl_xor(sS.x, 16); sS.x += __shfl_xor(sS.x, 32);
    sS.y += __shfl_xor(sS.y, 16); sS.y += __shfl_xor(sS.y, 32);
    sS.z += __shfl_xor(sS.z, 16); sS.z += __shfl_xor(sS.z, 32);
    sS.w += __shfl_xor(sS.w, 16); sS.w += __shfl_xor(sS.w, 32);
    sQ.x += __shfl_xor(sQ.x, 16); sQ.x += __shfl_xor(sQ.x, 32);
    sQ.y += __shfl_xor(sQ.y, 16); sQ.y += __shfl_xor(sQ.y, 32);
    sQ.z += __shfl_xor(sQ.z, 16); sQ.z += __shfl_xor(sQ.z, 32);
    sQ.w += __shfl_xor(sQ.w, 16); sQ.w += __shfl_xor(sQ.w, 32);
    if (sub == 0) {
        lds_red[wave][4 * li + 0] = sS.x;
        lds_red[wave][4 * li + 1] = sS.y;
        lds_red[wave][4 * li + 2] = sS.z;
        lds_red[wave][4 * li + 3] = sS.w;
        lds_red[wave][64 + 4 * li + 0] = sQ.x;
        lds_red[wave][64 + 4 * li + 1] = sQ.y;
        lds_red[wave][64 + 4 * li + 2] = sQ.z;
        lds_red[wave][64 + 4 * li + 3] = sQ.w;
    }
    __syncthreads();
    if (threadIdx.x < 128) {
        float v = lds_red[0][threadIdx.x] + lds_red[1][threadIdx.x] +
                  lds_red[2][threadIdx.x] + lds_red[3][threadIdx.x];
        atomicAdd(&bnacc[(blockIdx.x & (NSHADOW - 1)) * 128 + threadIdx.x], v);
    }
}

// Kernel C: scale/shift from BN stats; h2 = relu(bn(h1))@W2 + b2; x[node] = h2.
__global__ __launch_bounds__(256) void k_gin_c(
    float* __restrict__ xw, const int* __restrict__ clist_c,
    const int* __restrict__ ccount_c, const float* __restrict__ g1,
    const float* __restrict__ be1, const float* __restrict__ W2,
    const float* __restrict__ b2, const float* __restrict__ h1buf,
    const float* __restrict__ bnacc) {
    __shared__ float lds_scale[64];
    __shared__ float lds_shift[64];
    const int cnt = *ccount_c;
    const int lane = threadIdx.x & 63;
    const int wave = threadIdx.x >> 6;
    const int li = lane & 15;
    const int sub = lane >> 4;
    const int wid = blockIdx.x * 4 + wave;
    const int nwaves = gridDim.x * 4;
    const float4* __restrict__ h1buf4 = (const float4*)h1buf;
    const float4* __restrict__ W24 = (const float4*)W2;
    const float4* __restrict__ b24 = (const float4*)b2;
    float4* __restrict__ xw4 = (float4*)xw;

    if (threadIdx.x < 64) {
        float s = 0.f, q = 0.f;
        #pragma unroll
        for (int sh = 0; sh < NSHADOW; sh++) {
            s += bnacc[sh * 128 + threadIdx.x];
            q += bnacc[sh * 128 + 64 + threadIdx.x];
        }
        float fc = fmaxf((float)cnt, 1.f);
        float mean = s / fc;
        float var = q / fc - mean * mean;
        float sc = g1[threadIdx.x] * rsqrtf(var + BN_EPS);
        lds_scale[threadIdx.x] = sc;
        lds_shift[threadIdx.x] = be1[threadIdx.x] - mean * sc;
    }
    __syncthreads();
    for (int g0 = wid * 4; g0 < cnt; g0 += nwaves * 4) {
        int idx = g0 + sub;
        bool active = (idx < cnt);
        int eidx = active ? idx : 0;
        float4 hv = h1buf4[(size_t)eidx * 16 + li];
        float4 a;
        a.x = fmaxf(hv.x * lds_scale[4 * li + 0] + lds_shift[4 * li + 0], 0.f);
        a.y = fmaxf(hv.y * lds_scale[4 * li + 1] + lds_shift[4 * li + 1], 0.f);
        a.z = fmaxf(hv.z * lds_scale[4 * li + 2] + lds_shift[4 * li + 2], 0.f);
        a.w = fmaxf(hv.w * lds_scale[4 * li + 3] + lds_shift[4 * li + 3], 0.f);
        float4 s = b24[li];
        #pragma unroll
        for (int k = 0; k < 16; k++) {
            float h0 = __shfl(a.x, sub * 16 + k);
            float h1v = __shfl(a.y, sub * 16 + k);
            float h2 = __shfl(a.z, sub * 16 + k);
            float h3 = __shfl(a.w, sub * 16 + k);
            float4 w0 = W24[(4 * k + 0) * 16 + li];
            float4 w1 = W24[(4 * k + 1) * 16 + li];
            float4 w2 = W24[(4 * k + 2) * 16 + li];
            float4 w3 = W24[(4 * k + 3) * 16 + li];
            s.x += h0 * w0.x + h1v * w1.x + h2 * w2.x + h3 * w3.x;
            s.y += h0 * w0.y + h1v * w1.y + h2 * w2.y + h3 * w3.y;
            s.z += h0 * w0.z + h1v * w1.z + h2 * w2.z + h3 * w3.z;
            s.w += h0 * w0.w + h1v * w1.w + h2 * w2.w + h3 * w3.w;
        }
        if (active) {
            int node = clist_c[idx];
            xw4[(size_t)node * 16 + li] = s;
        }
    }
}

// ---------------- pooling (batch is sorted) ----------------
__global__ void k_pool(const float* __restrict__ xw, const int* __restrict__ batch,
                       float* __restrict__ z, int t) {
    const int CHUNK = 64;
    int lane = threadIdx.x & 63;
    int wg = (blockIdx.x * blockDim.x + threadIdx.x) >> 6;
    int lo = wg * CHUNK;
    if (lo >= NN) return;
    int hi = min(lo + CHUNK, NN);
    float acc = 0.f;
    int curg = batch[lo];
    for (int n = lo; n < hi; n++) {
        int g = batch[n];
        if (g != curg) {
            atomicAdd(&z[curg * (HH * LL) + t * HH + lane], acc);
            acc = 0.f;
            curg = g;
        }
        acc += xw[(size_t)n * 64 + lane];
    }
    atomicAdd(&z[curg * (HH * LL) + t * HH + lane], acc);
}

// ---------------- final MLP (split for parallelism) ----------------
// k_final1: 64 blocks (one graph each): h[g] = z[g] @ Wp1 + bp1
__global__ __launch_bounds__(256) void k_final1(
    const float* __restrict__ z, const float* __restrict__ Wp1,
    const float* __restrict__ bp1, float* __restrict__ hbuf) {
    __shared__ float red[256];
    int g = blockIdx.x;
    int k = threadIdx.x & 63;
    int part = threadIdx.x >> 6;  // 4 parts x 48 j's
    float s = 0.f;
    #pragma unroll 8
    for (int j = part * 48; j < (part + 1) * 48; j++)
        s += z[g * (HH * LL) + j] * Wp1[j * 64 + k];
    red[threadIdx.x] = s;
    __syncthreads();
    if (part == 0)
        hbuf[g * 64 + k] = red[k] + red[64 + k] + red[128 + k] + red[192 + k] + bp1[k];
}

// k_final2: 1 block: BN over 64 graphs + ReLU + @Wp2 + bp2
__global__ __launch_bounds__(256) void k_final2(
    const float* __restrict__ hbuf, const float* __restrict__ gp,
    const float* __restrict__ bep, const float* __restrict__ Wp2,
    const float* __restrict__ bp2, float* __restrict__ out) {
    __shared__ float lds[64 * 64];
    __shared__ float sscale[64];
    __shared__ float sshift[64];
    int tid = threadIdx.x;
    for (int i = tid; i < 64 * 64; i += 256) lds[i] = hbuf[i];
    __syncthreads();
    if (tid < 64) {
        float s = 0.f, q = 0.f;
        for (int g = 0; g < 64; g++) { float v = lds[g * 64 + tid]; s += v; q += v * v; }
        float mean = s / 64.f;
        float var = q / 64.f - mean * mean;
        float sc = gp[tid] * rsqrtf(var + BN_EPS);
        sscale[tid] = sc;
        sshift[tid] = bep[tid] - mean * sc;
    }
    __syncthreads();
    for (int i = tid; i < 64 * 64; i += 256) {
        int k = i & 63;
        lds[i] = fmaxf(lds[i] * sscale[k] + sshift[k], 0.f);
    }
    __syncthreads();
    for (int i = tid; i < 64 * 64; i += 256) {
        int g = i >> 6, o = i & 63;
        float s = bp2[o];
        #pragma unroll 8
        for (int k = 0; k < 64; k++) s += lds[g * 64 + k] * Wp2[k * 64 + o];
        out[g * 64 + o] = s;
    }
}

// ---------------- launch ----------------
extern "C" void kernel_launch(void* const* d_in, const int* in_sizes, int n_in,
                              void* d_out, int out_size, void* d_ws, size_t ws_size,
                              hipStream_t stream) {
    const float* x_in = (const float*)d_in[0];
    const int* labels = (const int*)d_in[1];
    const int* esrc = (const int*)d_in[2];
    const int* edst = esrc + EE;
    const int* batch = (const int*)d_in[3];
    const float* W1 = (const float*)d_in[4];
    const float* b1 = (const float*)d_in[5];
    const float* g1 = (const float*)d_in[6];
    const float* be1 = (const float*)d_in[7];
    const float* W2 = (const float*)d_in[8];
    const float* b2 = (const float*)d_in[9];
    const float* Wp1 = (const float*)d_in[10];
    const float* bp1 = (const float*)d_in[11];
    const float* gp = (const float*)d_in[12];
    const float* bep = (const float*)d_in[13];
    const float* Wp2 = (const float*)d_in[14];
    const float* bp2 = (const float*)d_in[15];
    float* out = (float*)d_out;

    char* p = (char*)d_ws;
    auto carve = [&](size_t bytes) -> void* {
        void* r = (void*)p;
        p += (bytes + 255) & ~(size_t)255;
        return r;
    };
    // ---- zeroed region (one memset) ----
    float* bnacc = (float*)carve((size_t)LL * CC * NSHADOW * 128 * 4);
    float* z     = (float*)carve((size_t)GG * HH * LL * 4);
    int*   deg   = (int*)carve((size_t)NN * 4);
    size_t zero_bytes = (size_t)(p - (char*)d_ws);
    // ---- rest ----
    int*   ccount  = (int*)carve(CC * 4);
    int*   blockcnt= (int*)carve((size_t)CC * SBLK * 4);
    int*   coffs   = (int*)carve((size_t)CC * SBLK * 4);
    int*   dpart   = (int*)carve((size_t)SBLK * 4);
    int*   dbase   = (int*)carve((size_t)SBLK * 4);
    float* xw      = (float*)carve((size_t)NN * 64 * 4);
    float* h1buf   = (float*)carve((size_t)NN * 64 * 4);
    float* hbuf    = (float*)carve((size_t)GG * 64 * 4);
    int*   rowptr  = (int*)carve((size_t)(NN + 1) * 4);
    int*   cursor  = (int*)carve((size_t)NN * 4);
    int*   adj     = (int*)carve((size_t)EE * 4);
    int*   clist   = (int*)carve((size_t)CC * NN * 4);

    hipMemsetAsync(d_ws, 0, zero_bytes, stream);
    hipMemcpyAsync(xw, x_in, (size_t)NN * 64 * 4, hipMemcpyDeviceToDevice, stream);

    k_deghist<<<(EE + 255) / 256, 256, 0, stream>>>(edst, deg, labels, blockcnt);
    k_scancombo<<<SBLK + 1, 256, 0, stream>>>(deg, rowptr, dpart, blockcnt, coffs, ccount);
    k_dscan2<<<1, 256, 0, stream>>>(dpart, dbase, rowptr);
    k_cfill_dscan3<<<SBLK, 256, 0, stream>>>(rowptr, dbase, cursor, labels, coffs, clist);
    k_fill<<<(EE + 255) / 256, 256, 0, stream>>>(esrc, edst, cursor, adj);

    for (int t = 0; t < LL; t++) {
        for (int c = 0; c < CC; c++) {
            int tc = t * CC + c;
            k_gin_a<<<GIN_BLOCKS, 256, 0, stream>>>(
                xw, adj, rowptr, clist + c * NN, ccount + c,
                W1 + (size_t)tc * 4096, b1 + (size_t)tc * 64, h1buf,
                bnacc + (size_t)tc * NSHADOW * 128);
            k_gin_c<<<GIN_BLOCKS, 256, 0, stream>>>(
                xw, clist + c * NN, ccount + c,
                g1 + (size_t)tc * 64, be1 + (size_t)tc * 64,
                W2 + (size_t)tc * 4096, b2 + (size_t)tc * 64, h1buf,
                bnacc + (size_t)tc * NSHADOW * 128);
        }
        int pool_waves = (NN + 63) / 64;
        int pool_blocks = (pool_waves * 64 + 255) / 256;
        k_pool<<<pool_blocks, 256, 0, stream>>>(xw, batch, z, t);
    }
    k_final1<<<GG, 256, 0, stream>>>(z, Wp1, bp1, hbuf);
    k_final2<<<1, 256, 0, stream>>>(hbuf, gp, bep, Wp2, bp2, out);
}

// Round 8
// 830.015 us; speedup vs baseline: 1.3199x; 1.3199x over previous
//
#include <hip/hip_runtime.h>
#include <hip/hip_bf16.h>

#define NN 50000
#define EE 800000
#define GG 64
#define LL 3
#define CC 4
#define HH 64
#define BN_EPS 1e-5f
#define NSHADOW 16
#define SBLK 196          // ceil(NN/256) node-parallel blocks
#define GIN_BLOCKS 2048   // grid-stride GIN kernels (8192 waves = 32 waves/CU)

// NOTE: harness passes ALL integer inputs as int32 (edge_index/batch included).
// NOTE: cooperative launch + grid.sync measured 4x SLOWER than kernel-boundary
//       barriers on this problem (R5: 5154us vs 1230us) — do not reintroduce.
// NOTE: single-block k_final measured 90us (latency-bound) — keep final MLP split (R7).
// NOTE: 4-nodes/wave float4 GIN layout at 800 blocks measured +280us vs scalar
//       layout at 2048 blocks (R7: TLP starvation) — keep 1 node/wave + big grid.

// ---------------- setup kernels ----------------

__global__ void k_deghist(const int* __restrict__ dst, int* __restrict__ deg,
                          const int* __restrict__ labels, int* __restrict__ blockcnt) {
    __shared__ int cnt[CC];
    int tid = threadIdx.x;
    bool hist = (blockIdx.x < SBLK);
    if (hist && tid < CC) cnt[tid] = 0;
    __syncthreads();
    int gid = blockIdx.x * 256 + tid;
    if (gid < EE) atomicAdd(&deg[dst[gid]], 1);
    if (hist && gid < NN) atomicAdd(&cnt[labels[gid]], 1);
    __syncthreads();
    if (hist && tid < CC) blockcnt[tid * SBLK + blockIdx.x] = cnt[tid];
}

__global__ __launch_bounds__(256) void k_scancombo(
    const int* __restrict__ deg, int* __restrict__ rowptr, int* __restrict__ dpart,
    const int* __restrict__ blockcnt, int* __restrict__ coffs, int* __restrict__ ccount) {
    __shared__ int smem[CC * 256];
    int tid = threadIdx.x;
    if (blockIdx.x < SBLK) {
        int i = blockIdx.x * 256 + tid;
        int v = (i < NN) ? deg[i] : 0;
        smem[tid] = v;
        __syncthreads();
        for (int off = 1; off < 256; off <<= 1) {
            int u = (tid >= off) ? smem[tid - off] : 0;
            __syncthreads();
            smem[tid] += u;
            __syncthreads();
        }
        if (i < NN) rowptr[i] = smem[tid] - v;  // local exclusive
        if (tid == 255) dpart[blockIdx.x] = smem[255];
    } else {
        int own[CC];
        for (int c = 0; c < CC; c++) {
            own[c] = (tid < SBLK) ? blockcnt[c * SBLK + tid] : 0;
            smem[c * 256 + tid] = own[c];
        }
        __syncthreads();
        for (int off = 1; off < 256; off <<= 1) {
            int v[CC];
            for (int c = 0; c < CC; c++) v[c] = (tid >= off) ? smem[c * 256 + tid - off] : 0;
            __syncthreads();
            for (int c = 0; c < CC; c++) smem[c * 256 + tid] += v[c];
            __syncthreads();
        }
        if (tid < SBLK)
            for (int c = 0; c < CC; c++) coffs[c * SBLK + tid] = smem[c * 256 + tid] - own[c];
        if (tid == 0)
            for (int c = 0; c < CC; c++) ccount[c] = smem[c * 256 + 255];
    }
}

__global__ __launch_bounds__(256) void k_dscan2(int* __restrict__ dpart,
                                                int* __restrict__ dbase,
                                                int* __restrict__ rowptr) {
    __shared__ int s[256];
    int tid = threadIdx.x;
    int v = (tid < SBLK) ? dpart[tid] : 0;
    s[tid] = v;
    __syncthreads();
    for (int off = 1; off < 256; off <<= 1) {
        int u = (tid >= off) ? s[tid - off] : 0;
        __syncthreads();
        s[tid] += u;
        __syncthreads();
    }
    if (tid < SBLK) dbase[tid] = s[tid] - v;
    if (tid == 0) rowptr[NN] = EE;
}

__global__ __launch_bounds__(256) void k_cfill_dscan3(
    int* __restrict__ rowptr, const int* __restrict__ dbase, int* __restrict__ cursor,
    const int* __restrict__ labels, const int* __restrict__ coffs, int* __restrict__ clist) {
    __shared__ int pos[CC];
    int tid = threadIdx.x;
    if (tid < CC) pos[tid] = coffs[tid * SBLK + blockIdx.x];
    __syncthreads();
    int i = blockIdx.x * 256 + tid;
    if (i < NN) {
        int r = rowptr[i] + dbase[blockIdx.x];
        rowptr[i] = r;
        cursor[i] = r;
        int c = labels[i];
        int p = atomicAdd(&pos[c], 1);
        clist[c * NN + p] = i;
    }
}

__global__ void k_fill(const int* __restrict__ src, const int* __restrict__ dst,
                       int* __restrict__ cursor, int* __restrict__ adj) {
    int e = blockIdx.x * blockDim.x + threadIdx.x;
    if (e < EE) {
        int d = dst[e];
        int pos = atomicAdd(&cursor[d], 1);
        adj[pos] = src[e];
    }
}

// ---------------- per-(t,c) kernels (R6-proven scalar layout) ----------------
// Kernel A: agg (CSR gather, 8 indep chains) + h1 = (agg+x)@W1 + b1; BN partials.
__global__ __launch_bounds__(256) void k_gin_a(
    const float* __restrict__ xw, const int* __restrict__ adj,
    const int* __restrict__ rowptr, const int* __restrict__ clist_c,
    const int* __restrict__ ccount_c, const float* __restrict__ W1,
    const float* __restrict__ b1, float* __restrict__ h1buf,
    float* __restrict__ bnacc) {
    __shared__ float lds_red[4][128];
    int cnt = *ccount_c;
    int lane = threadIdx.x & 63;
    int wave = threadIdx.x >> 6;
    int nwaves = gridDim.x * 4;
    float sS = 0.f, sQ = 0.f;
    int idx = blockIdx.x * 4 + wave;
    int node_next = (idx < cnt) ? clist_c[idx] : 0;
    for (; idx < cnt; idx += nwaves) {
        int node = node_next;
        int nidx = idx + nwaves;
        if (nidx < cnt) node_next = clist_c[nidx];  // prefetch next node id
        int rb = rowptr[node], re = rowptr[node + 1];
        float a0 = xw[node * 64 + lane];
        float a1 = 0.f, a2 = 0.f, a3 = 0.f, a4 = 0.f, a5 = 0.f, a6 = 0.f, a7 = 0.f;
        int base = rb, rem = re - rb;
        while (rem > 0) {
            int take = min(rem, 64);
            int nb = adj[base + min(lane, take - 1)];
            int j = 0;
            for (; j + 8 <= take; j += 8) {
                int n0 = __shfl(nb, j + 0);
                int n1 = __shfl(nb, j + 1);
                int n2 = __shfl(nb, j + 2);
                int n3 = __shfl(nb, j + 3);
                int n4 = __shfl(nb, j + 4);
                int n5 = __shfl(nb, j + 5);
                int n6 = __shfl(nb, j + 6);
                int n7 = __shfl(nb, j + 7);
                a0 += xw[n0 * 64 + lane];
                a1 += xw[n1 * 64 + lane];
                a2 += xw[n2 * 64 + lane];
                a3 += xw[n3 * 64 + lane];
                a4 += xw[n4 * 64 + lane];
                a5 += xw[n5 * 64 + lane];
                a6 += xw[n6 * 64 + lane];
                a7 += xw[n7 * 64 + lane];
            }
            for (; j < take; j++) a0 += xw[__shfl(nb, j) * 64 + lane];
            base += take; rem -= take;
        }
        float acc = ((a0 + a1) + (a2 + a3)) + ((a4 + a5) + (a6 + a7));
        float s = b1[lane];
        #pragma unroll
        for (int j = 0; j < 64; j++) s += __shfl(acc, j) * W1[j * 64 + lane];
        h1buf[(size_t)idx * 64 + lane] = s;
        sS += s; sQ += s * s;
    }
    lds_red[wave][lane] = sS;
    lds_red[wave][64 + lane] = sQ;
    __syncthreads();
    if (threadIdx.x < 128) {
        float v = lds_red[0][threadIdx.x] + lds_red[1][threadIdx.x] +
                  lds_red[2][threadIdx.x] + lds_red[3][threadIdx.x];
        atomicAdd(&bnacc[(blockIdx.x & (NSHADOW - 1)) * 128 + threadIdx.x], v);
    }
}

// Kernel C: scale/shift from BN stats; h2 = relu(bn(h1))@W2 + b2; x[node] = h2.
__global__ __launch_bounds__(256) void k_gin_c(
    float* __restrict__ xw, const int* __restrict__ clist_c,
    const int* __restrict__ ccount_c, const float* __restrict__ g1,
    const float* __restrict__ be1, const float* __restrict__ W2,
    const float* __restrict__ b2, const float* __restrict__ h1buf,
    const float* __restrict__ bnacc) {
    __shared__ float lds_scale[64];
    __shared__ float lds_shift[64];
    int cnt = *ccount_c;
    int lane = threadIdx.x & 63;
    int wave = threadIdx.x >> 6;
    if (threadIdx.x < 64) {
        float s = 0.f, q = 0.f;
        #pragma unroll
        for (int sh = 0; sh < NSHADOW; sh++) {
            s += bnacc[sh * 128 + threadIdx.x];
            q += bnacc[sh * 128 + 64 + threadIdx.x];
        }
        float fc = fmaxf((float)cnt, 1.f);
        float mean = s / fc;
        float var = q / fc - mean * mean;
        float sc = g1[threadIdx.x] * rsqrtf(var + BN_EPS);
        lds_scale[threadIdx.x] = sc;
        lds_shift[threadIdx.x] = be1[threadIdx.x] - mean * sc;
    }
    __syncthreads();
    int nwaves = gridDim.x * 4;
    for (int idx = blockIdx.x * 4 + wave; idx < cnt; idx += nwaves) {
        float h = h1buf[(size_t)idx * 64 + lane];
        float a = fmaxf(h * lds_scale[lane] + lds_shift[lane], 0.f);
        float s = b2[lane];
        #pragma unroll
        for (int j = 0; j < 64; j++) s += __shfl(a, j) * W2[j * 64 + lane];
        xw[(size_t)clist_c[idx] * 64 + lane] = s;
    }
}

// ---------------- pooling (batch is sorted) ----------------
__global__ void k_pool(const float* __restrict__ xw, const int* __restrict__ batch,
                       float* __restrict__ z, int t) {
    const int CHUNK = 64;
    int lane = threadIdx.x & 63;
    int wg = (blockIdx.x * blockDim.x + threadIdx.x) >> 6;
    int lo = wg * CHUNK;
    if (lo >= NN) return;
    int hi = min(lo + CHUNK, NN);
    float acc = 0.f;
    int curg = batch[lo];
    for (int n = lo; n < hi; n++) {
        int g = batch[n];
        if (g != curg) {
            atomicAdd(&z[curg * (HH * LL) + t * HH + lane], acc);
            acc = 0.f;
            curg = g;
        }
        acc += xw[(size_t)n * 64 + lane];
    }
    atomicAdd(&z[curg * (HH * LL) + t * HH + lane], acc);
}

// ---------------- final MLP (split for parallelism, R7-proven) ----------------
__global__ __launch_bounds__(256) void k_final1(
    const float* __restrict__ z, const float* __restrict__ Wp1,
    const float* __restrict__ bp1, float* __restrict__ hbuf) {
    __shared__ float red[256];
    int g = blockIdx.x;
    int k = threadIdx.x & 63;
    int part = threadIdx.x >> 6;  // 4 parts x 48 j's
    float s = 0.f;
    #pragma unroll 8
    for (int j = part * 48; j < (part + 1) * 48; j++)
        s += z[g * (HH * LL) + j] * Wp1[j * 64 + k];
    red[threadIdx.x] = s;
    __syncthreads();
    if (part == 0)
        hbuf[g * 64 + k] = red[k] + red[64 + k] + red[128 + k] + red[192 + k] + bp1[k];
}

__global__ __launch_bounds__(256) void k_final2(
    const float* __restrict__ hbuf, const float* __restrict__ gp,
    const float* __restrict__ bep, const float* __restrict__ Wp2,
    const float* __restrict__ bp2, float* __restrict__ out) {
    __shared__ float lds[64 * 64];
    __shared__ float sscale[64];
    __shared__ float sshift[64];
    int tid = threadIdx.x;
    for (int i = tid; i < 64 * 64; i += 256) lds[i] = hbuf[i];
    __syncthreads();
    if (tid < 64) {
        float s = 0.f, q = 0.f;
        for (int g = 0; g < 64; g++) { float v = lds[g * 64 + tid]; s += v; q += v * v; }
        float mean = s / 64.f;
        float var = q / 64.f - mean * mean;
        float sc = gp[tid] * rsqrtf(var + BN_EPS);
        sscale[tid] = sc;
        sshift[tid] = bep[tid] - mean * sc;
    }
    __syncthreads();
    for (int i = tid; i < 64 * 64; i += 256) {
        int k = i & 63;
        lds[i] = fmaxf(lds[i] * sscale[k] + sshift[k], 0.f);
    }
    __syncthreads();
    for (int i = tid; i < 64 * 64; i += 256) {
        int g = i >> 6, o = i & 63;
        float s = bp2[o];
        #pragma unroll 8
        for (int k = 0; k < 64; k++) s += lds[g * 64 + k] * Wp2[k * 64 + o];
        out[g * 64 + o] = s;
    }
}

// ---------------- launch ----------------
extern "C" void kernel_launch(void* const* d_in, const int* in_sizes, int n_in,
                              void* d_out, int out_size, void* d_ws, size_t ws_size,
                              hipStream_t stream) {
    const float* x_in = (const float*)d_in[0];
    const int* labels = (const int*)d_in[1];
    const int* esrc = (const int*)d_in[2];
    const int* edst = esrc + EE;
    const int* batch = (const int*)d_in[3];
    const float* W1 = (const float*)d_in[4];
    const float* b1 = (const float*)d_in[5];
    const float* g1 = (const float*)d_in[6];
    const float* be1 = (const float*)d_in[7];
    const float* W2 = (const float*)d_in[8];
    const float* b2 = (const float*)d_in[9];
    const float* Wp1 = (const float*)d_in[10];
    const float* bp1 = (const float*)d_in[11];
    const float* gp = (const float*)d_in[12];
    const float* bep = (const float*)d_in[13];
    const float* Wp2 = (const float*)d_in[14];
    const float* bp2 = (const float*)d_in[15];
    float* out = (float*)d_out;

    char* p = (char*)d_ws;
    auto carve = [&](size_t bytes) -> void* {
        void* r = (void*)p;
        p += (bytes + 255) & ~(size_t)255;
        return r;
    };
    // ---- zeroed region (one memset) ----
    float* bnacc = (float*)carve((size_t)LL * CC * NSHADOW * 128 * 4);
    float* z     = (float*)carve((size_t)GG * HH * LL * 4);
    int*   deg   = (int*)carve((size_t)NN * 4);
    size_t zero_bytes = (size_t)(p - (char*)d_ws);
    // ---- rest ----
    int*   ccount  = (int*)carve(CC * 4);
    int*   blockcnt= (int*)carve((size_t)CC * SBLK * 4);
    int*   coffs   = (int*)carve((size_t)CC * SBLK * 4);
    int*   dpart   = (int*)carve((size_t)SBLK * 4);
    int*   dbase   = (int*)carve((size_t)SBLK * 4);
    float* xw      = (float*)carve((size_t)NN * 64 * 4);
    float* h1buf   = (float*)carve((size_t)NN * 64 * 4);
    float* hbuf    = (float*)carve((size_t)GG * 64 * 4);
    int*   rowptr  = (int*)carve((size_t)(NN + 1) * 4);
    int*   cursor  = (int*)carve((size_t)NN * 4);
    int*   adj     = (int*)carve((size_t)EE * 4);
    int*   clist   = (int*)carve((size_t)CC * NN * 4);

    hipMemsetAsync(d_ws, 0, zero_bytes, stream);
    hipMemcpyAsync(xw, x_in, (size_t)NN * 64 * 4, hipMemcpyDeviceToDevice, stream);

    k_deghist<<<(EE + 255) / 256, 256, 0, stream>>>(edst, deg, labels, blockcnt);
    k_scancombo<<<SBLK + 1, 256, 0, stream>>>(deg, rowptr, dpart, blockcnt, coffs, ccount);
    k_dscan2<<<1, 256, 0, stream>>>(dpart, dbase, rowptr);
    k_cfill_dscan3<<<SBLK, 256, 0, stream>>>(rowptr, dbase, cursor, labels, coffs, clist);
    k_fill<<<(EE + 255) / 256, 256, 0, stream>>>(esrc, edst, cursor, adj);

    for (int t = 0; t < LL; t++) {
        for (int c = 0; c < CC; c++) {
            int tc = t * CC + c;
            k_gin_a<<<GIN_BLOCKS, 256, 0, stream>>>(
                xw, adj, rowptr, clist + c * NN, ccount + c,
                W1 + (size_t)tc * 4096, b1 + (size_t)tc * 64, h1buf,
                bnacc + (size_t)tc * NSHADOW * 128);
            k_gin_c<<<GIN_BLOCKS, 256, 0, stream>>>(
                xw, clist + c * NN, ccount + c,
                g1 + (size_t)tc * 64, be1 + (size_t)tc * 64,
                W2 + (size_t)tc * 4096, b2 + (size_t)tc * 64, h1buf,
                bnacc + (size_t)tc * NSHADOW * 128);
        }
        int pool_waves = (NN + 63) / 64;
        int pool_blocks = (pool_waves * 64 + 255) / 256;
        k_pool<<<pool_blocks, 256, 0, stream>>>(xw, batch, z, t);
    }
    k_final1<<<GG, 256, 0, stream>>>(z, Wp1, bp1, hbuf);
    k_final2<<<1, 256, 0, stream>>>(hbuf, gp, bep, Wp2, bp2, out);
}

// Round 9
// 733.184 us; speedup vs baseline: 1.4942x; 1.1321x over previous
//
#include <hip/hip_runtime.h>
#include <hip/hip_bf16.h>

#define NN 50000
#define EE 800000
#define GG 64
#define LL 3
#define CC 4
#define HH 64
#define BN_EPS 1e-5f
#define NSHADOW 16
#define SBLK 196          // ceil(NN/256) node-parallel blocks
#define GIN_BLOCKS 2048   // grid-stride GIN kernels (8192 waves = 32 waves/CU)

// NOTE: harness passes ALL integer inputs as int32 (edge_index/batch included).
// NOTE: cooperative launch + grid.sync measured 4x SLOWER than kernel-boundary
//       barriers (R5: 5154us vs 1230us) — do not reintroduce.
// NOTE: single-block k_final measured 90us (latency-bound) — keep final MLP split (R7).
// NOTE: 4-nodes/wave float4 GIN layout at 800 blocks measured +280us vs scalar
//       layout at 2048 blocks (R7: TLP starvation) — keep 1 node/wave + big grid.
// NOTE: R8 counters: k_gin_a FETCH 22.8 MB/dispatch (scatter-gather memory-bound)
//       -> xw stored as bf16 (R9), arithmetic stays fp32.

// ---------------- setup kernels ----------------

__global__ void k_deghist(const int* __restrict__ dst, int* __restrict__ deg,
                          const int* __restrict__ labels, int* __restrict__ blockcnt) {
    __shared__ int cnt[CC];
    int tid = threadIdx.x;
    bool hist = (blockIdx.x < SBLK);
    if (hist && tid < CC) cnt[tid] = 0;
    __syncthreads();
    int gid = blockIdx.x * 256 + tid;
    if (gid < EE) atomicAdd(&deg[dst[gid]], 1);
    if (hist && gid < NN) atomicAdd(&cnt[labels[gid]], 1);
    __syncthreads();
    if (hist && tid < CC) blockcnt[tid * SBLK + blockIdx.x] = cnt[tid];
}

__global__ __launch_bounds__(256) void k_scancombo(
    const int* __restrict__ deg, int* __restrict__ rowptr, int* __restrict__ dpart,
    const int* __restrict__ blockcnt, int* __restrict__ coffs, int* __restrict__ ccount) {
    __shared__ int smem[CC * 256];
    int tid = threadIdx.x;
    if (blockIdx.x < SBLK) {
        int i = blockIdx.x * 256 + tid;
        int v = (i < NN) ? deg[i] : 0;
        smem[tid] = v;
        __syncthreads();
        for (int off = 1; off < 256; off <<= 1) {
            int u = (tid >= off) ? smem[tid - off] : 0;
            __syncthreads();
            smem[tid] += u;
            __syncthreads();
        }
        if (i < NN) rowptr[i] = smem[tid] - v;  // local exclusive
        if (tid == 255) dpart[blockIdx.x] = smem[255];
    } else {
        int own[CC];
        for (int c = 0; c < CC; c++) {
            own[c] = (tid < SBLK) ? blockcnt[c * SBLK + tid] : 0;
            smem[c * 256 + tid] = own[c];
        }
        __syncthreads();
        for (int off = 1; off < 256; off <<= 1) {
            int v[CC];
            for (int c = 0; c < CC; c++) v[c] = (tid >= off) ? smem[c * 256 + tid - off] : 0;
            __syncthreads();
            for (int c = 0; c < CC; c++) smem[c * 256 + tid] += v[c];
            __syncthreads();
        }
        if (tid < SBLK)
            for (int c = 0; c < CC; c++) coffs[c * SBLK + tid] = smem[c * 256 + tid] - own[c];
        if (tid == 0)
            for (int c = 0; c < CC; c++) ccount[c] = smem[c * 256 + 255];
    }
}

__global__ __launch_bounds__(256) void k_dscan2(int* __restrict__ dpart,
                                                int* __restrict__ dbase,
                                                int* __restrict__ rowptr) {
    __shared__ int s[256];
    int tid = threadIdx.x;
    int v = (tid < SBLK) ? dpart[tid] : 0;
    s[tid] = v;
    __syncthreads();
    for (int off = 1; off < 256; off <<= 1) {
        int u = (tid >= off) ? s[tid - off] : 0;
        __syncthreads();
        s[tid] += u;
        __syncthreads();
    }
    if (tid < SBLK) dbase[tid] = s[tid] - v;
    if (tid == 0) rowptr[NN] = EE;
}

__global__ __launch_bounds__(256) void k_cfill_dscan3(
    int* __restrict__ rowptr, const int* __restrict__ dbase, int* __restrict__ cursor,
    const int* __restrict__ labels, const int* __restrict__ coffs, int* __restrict__ clist) {
    __shared__ int pos[CC];
    int tid = threadIdx.x;
    if (tid < CC) pos[tid] = coffs[tid * SBLK + blockIdx.x];
    __syncthreads();
    int i = blockIdx.x * 256 + tid;
    if (i < NN) {
        int r = rowptr[i] + dbase[blockIdx.x];
        rowptr[i] = r;
        cursor[i] = r;
        int c = labels[i];
        int p = atomicAdd(&pos[c], 1);
        clist[c * NN + p] = i;
    }
}

__global__ void k_fill(const int* __restrict__ src, const int* __restrict__ dst,
                       int* __restrict__ cursor, int* __restrict__ adj) {
    int e = blockIdx.x * blockDim.x + threadIdx.x;
    if (e < EE) {
        int d = dst[e];
        int pos = atomicAdd(&cursor[d], 1);
        adj[pos] = src[e];
    }
}

// fp32 -> bf16 conversion of x into xw
__global__ void k_cvt(const float* __restrict__ x_in, __hip_bfloat16* __restrict__ xw) {
    int i = blockIdx.x * blockDim.x + threadIdx.x;
    if (i < NN * 64) xw[i] = __float2bfloat16(x_in[i]);
}

// ---------------- per-(t,c) kernels (scalar layout, bf16 xw) ----------------
// Kernel A: agg (CSR gather, 8 indep chains) + h1 = (agg+x)@W1 + b1; BN partials.
__global__ __launch_bounds__(256) void k_gin_a(
    const __hip_bfloat16* __restrict__ xw, const int* __restrict__ adj,
    const int* __restrict__ rowptr, const int* __restrict__ clist_c,
    const int* __restrict__ ccount_c, const float* __restrict__ W1,
    const float* __restrict__ b1, float* __restrict__ h1buf,
    float* __restrict__ bnacc) {
    __shared__ float lds_red[4][128];
    int cnt = *ccount_c;
    int lane = threadIdx.x & 63;
    int wave = threadIdx.x >> 6;
    int nwaves = gridDim.x * 4;
    float sS = 0.f, sQ = 0.f;
    int idx = blockIdx.x * 4 + wave;
    int node_next = (idx < cnt) ? clist_c[idx] : 0;
    for (; idx < cnt; idx += nwaves) {
        int node = node_next;
        int nidx = idx + nwaves;
        if (nidx < cnt) node_next = clist_c[nidx];  // prefetch next node id
        int rb = rowptr[node], re = rowptr[node + 1];
        float a0 = __bfloat162float(xw[(size_t)node * 64 + lane]);
        float a1 = 0.f, a2 = 0.f, a3 = 0.f, a4 = 0.f, a5 = 0.f, a6 = 0.f, a7 = 0.f;
        int base = rb, rem = re - rb;
        while (rem > 0) {
            int take = min(rem, 64);
            int nb = adj[base + min(lane, take - 1)];
            int j = 0;
            for (; j + 8 <= take; j += 8) {
                int n0 = __shfl(nb, j + 0);
                int n1 = __shfl(nb, j + 1);
                int n2 = __shfl(nb, j + 2);
                int n3 = __shfl(nb, j + 3);
                int n4 = __shfl(nb, j + 4);
                int n5 = __shfl(nb, j + 5);
                int n6 = __shfl(nb, j + 6);
                int n7 = __shfl(nb, j + 7);
                a0 += __bfloat162float(xw[(size_t)n0 * 64 + lane]);
                a1 += __bfloat162float(xw[(size_t)n1 * 64 + lane]);
                a2 += __bfloat162float(xw[(size_t)n2 * 64 + lane]);
                a3 += __bfloat162float(xw[(size_t)n3 * 64 + lane]);
                a4 += __bfloat162float(xw[(size_t)n4 * 64 + lane]);
                a5 += __bfloat162float(xw[(size_t)n5 * 64 + lane]);
                a6 += __bfloat162float(xw[(size_t)n6 * 64 + lane]);
                a7 += __bfloat162float(xw[(size_t)n7 * 64 + lane]);
            }
            for (; j < take; j++)
                a0 += __bfloat162float(xw[(size_t)__shfl(nb, j) * 64 + lane]);
            base += take; rem -= take;
        }
        float acc = ((a0 + a1) + (a2 + a3)) + ((a4 + a5) + (a6 + a7));
        float s = b1[lane];
        #pragma unroll
        for (int j = 0; j < 64; j++) s += __shfl(acc, j) * W1[j * 64 + lane];
        h1buf[(size_t)idx * 64 + lane] = s;
        sS += s; sQ += s * s;
    }
    lds_red[wave][lane] = sS;
    lds_red[wave][64 + lane] = sQ;
    __syncthreads();
    if (threadIdx.x < 128) {
        float v = lds_red[0][threadIdx.x] + lds_red[1][threadIdx.x] +
                  lds_red[2][threadIdx.x] + lds_red[3][threadIdx.x];
        atomicAdd(&bnacc[(blockIdx.x & (NSHADOW - 1)) * 128 + threadIdx.x], v);
    }
}

// Kernel C: scale/shift from BN stats; h2 = relu(bn(h1))@W2 + b2; x[node] = h2 (bf16).
__global__ __launch_bounds__(256) void k_gin_c(
    __hip_bfloat16* __restrict__ xw, const int* __restrict__ clist_c,
    const int* __restrict__ ccount_c, const float* __restrict__ g1,
    const float* __restrict__ be1, const float* __restrict__ W2,
    const float* __restrict__ b2, const float* __restrict__ h1buf,
    const float* __restrict__ bnacc) {
    __shared__ float lds_scale[64];
    __shared__ float lds_shift[64];
    int cnt = *ccount_c;
    int lane = threadIdx.x & 63;
    int wave = threadIdx.x >> 6;
    if (threadIdx.x < 64) {
        float s = 0.f, q = 0.f;
        #pragma unroll
        for (int sh = 0; sh < NSHADOW; sh++) {
            s += bnacc[sh * 128 + threadIdx.x];
            q += bnacc[sh * 128 + 64 + threadIdx.x];
        }
        float fc = fmaxf((float)cnt, 1.f);
        float mean = s / fc;
        float var = q / fc - mean * mean;
        float sc = g1[threadIdx.x] * rsqrtf(var + BN_EPS);
        lds_scale[threadIdx.x] = sc;
        lds_shift[threadIdx.x] = be1[threadIdx.x] - mean * sc;
    }
    __syncthreads();
    int nwaves = gridDim.x * 4;
    for (int idx = blockIdx.x * 4 + wave; idx < cnt; idx += nwaves) {
        float h = h1buf[(size_t)idx * 64 + lane];
        float a = fmaxf(h * lds_scale[lane] + lds_shift[lane], 0.f);
        float s = b2[lane];
        #pragma unroll
        for (int j = 0; j < 64; j++) s += __shfl(a, j) * W2[j * 64 + lane];
        xw[(size_t)clist_c[idx] * 64 + lane] = __float2bfloat16(s);
    }
}

// ---------------- pooling (batch is sorted) ----------------
__global__ void k_pool(const __hip_bfloat16* __restrict__ xw, const int* __restrict__ batch,
                       float* __restrict__ z, int t) {
    const int CHUNK = 64;
    int lane = threadIdx.x & 63;
    int wg = (blockIdx.x * blockDim.x + threadIdx.x) >> 6;
    int lo = wg * CHUNK;
    if (lo >= NN) return;
    int hi = min(lo + CHUNK, NN);
    float acc = 0.f;
    int curg = batch[lo];
    for (int n = lo; n < hi; n++) {
        int g = batch[n];
        if (g != curg) {
            atomicAdd(&z[curg * (HH * LL) + t * HH + lane], acc);
            acc = 0.f;
            curg = g;
        }
        acc += __bfloat162float(xw[(size_t)n * 64 + lane]);
    }
    atomicAdd(&z[curg * (HH * LL) + t * HH + lane], acc);
}

// ---------------- final MLP (split for parallelism, R7-proven) ----------------
__global__ __launch_bounds__(256) void k_final1(
    const float* __restrict__ z, const float* __restrict__ Wp1,
    const float* __restrict__ bp1, float* __restrict__ hbuf) {
    __shared__ float red[256];
    int g = blockIdx.x;
    int k = threadIdx.x & 63;
    int part = threadIdx.x >> 6;  // 4 parts x 48 j's
    float s = 0.f;
    #pragma unroll 8
    for (int j = part * 48; j < (part + 1) * 48; j++)
        s += z[g * (HH * LL) + j] * Wp1[j * 64 + k];
    red[threadIdx.x] = s;
    __syncthreads();
    if (part == 0)
        hbuf[g * 64 + k] = red[k] + red[64 + k] + red[128 + k] + red[192 + k] + bp1[k];
}

__global__ __launch_bounds__(256) void k_final2(
    const float* __restrict__ hbuf, const float* __restrict__ gp,
    const float* __restrict__ bep, const float* __restrict__ Wp2,
    const float* __restrict__ bp2, float* __restrict__ out) {
    __shared__ float lds[64 * 64];
    __shared__ float sscale[64];
    __shared__ float sshift[64];
    int tid = threadIdx.x;
    for (int i = tid; i < 64 * 64; i += 256) lds[i] = hbuf[i];
    __syncthreads();
    if (tid < 64) {
        float s = 0.f, q = 0.f;
        for (int g = 0; g < 64; g++) { float v = lds[g * 64 + tid]; s += v; q += v * v; }
        float mean = s / 64.f;
        float var = q / 64.f - mean * mean;
        float sc = gp[tid] * rsqrtf(var + BN_EPS);
        sscale[tid] = sc;
        sshift[tid] = bep[tid] - mean * sc;
    }
    __syncthreads();
    for (int i = tid; i < 64 * 64; i += 256) {
        int k = i & 63;
        lds[i] = fmaxf(lds[i] * sscale[k] + sshift[k], 0.f);
    }
    __syncthreads();
    for (int i = tid; i < 64 * 64; i += 256) {
        int g = i >> 6, o = i & 63;
        float s = bp2[o];
        #pragma unroll 8
        for (int k = 0; k < 64; k++) s += lds[g * 64 + k] * Wp2[k * 64 + o];
        out[g * 64 + o] = s;
    }
}

// ---------------- launch ----------------
extern "C" void kernel_launch(void* const* d_in, const int* in_sizes, int n_in,
                              void* d_out, int out_size, void* d_ws, size_t ws_size,
                              hipStream_t stream) {
    const float* x_in = (const float*)d_in[0];
    const int* labels = (const int*)d_in[1];
    const int* esrc = (const int*)d_in[2];
    const int* edst = esrc + EE;
    const int* batch = (const int*)d_in[3];
    const float* W1 = (const float*)d_in[4];
    const float* b1 = (const float*)d_in[5];
    const float* g1 = (const float*)d_in[6];
    const float* be1 = (const float*)d_in[7];
    const float* W2 = (const float*)d_in[8];
    const float* b2 = (const float*)d_in[9];
    const float* Wp1 = (const float*)d_in[10];
    const float* bp1 = (const float*)d_in[11];
    const float* gp = (const float*)d_in[12];
    const float* bep = (const float*)d_in[13];
    const float* Wp2 = (const float*)d_in[14];
    const float* bp2 = (const float*)d_in[15];
    float* out = (float*)d_out;

    char* p = (char*)d_ws;
    auto carve = [&](size_t bytes) -> void* {
        void* r = (void*)p;
        p += (bytes + 255) & ~(size_t)255;
        return r;
    };
    // ---- zeroed region (one memset) ----
    float* bnacc = (float*)carve((size_t)LL * CC * NSHADOW * 128 * 4);
    float* z     = (float*)carve((size_t)GG * HH * LL * 4);
    int*   deg   = (int*)carve((size_t)NN * 4);
    size_t zero_bytes = (size_t)(p - (char*)d_ws);
    // ---- rest ----
    int*   ccount  = (int*)carve(CC * 4);
    int*   blockcnt= (int*)carve((size_t)CC * SBLK * 4);
    int*   coffs   = (int*)carve((size_t)CC * SBLK * 4);
    int*   dpart   = (int*)carve((size_t)SBLK * 4);
    int*   dbase   = (int*)carve((size_t)SBLK * 4);
    __hip_bfloat16* xw = (__hip_bfloat16*)carve((size_t)NN * 64 * 2);
    float* h1buf   = (float*)carve((size_t)NN * 64 * 4);
    float* hbuf    = (float*)carve((size_t)GG * 64 * 4);
    int*   rowptr  = (int*)carve((size_t)(NN + 1) * 4);
    int*   cursor  = (int*)carve((size_t)NN * 4);
    int*   adj     = (int*)carve((size_t)EE * 4);
    int*   clist   = (int*)carve((size_t)CC * NN * 4);

    hipMemsetAsync(d_ws, 0, zero_bytes, stream);

    k_cvt<<<(NN * 64 + 255) / 256, 256, 0, stream>>>(x_in, xw);
    k_deghist<<<(EE + 255) / 256, 256, 0, stream>>>(edst, deg, labels, blockcnt);
    k_scancombo<<<SBLK + 1, 256, 0, stream>>>(deg, rowptr, dpart, blockcnt, coffs, ccount);
    k_dscan2<<<1, 256, 0, stream>>>(dpart, dbase, rowptr);
    k_cfill_dscan3<<<SBLK, 256, 0, stream>>>(rowptr, dbase, cursor, labels, coffs, clist);
    k_fill<<<(EE + 255) / 256, 256, 0, stream>>>(esrc, edst, cursor, adj);

    for (int t = 0; t < LL; t++) {
        for (int c = 0; c < CC; c++) {
            int tc = t * CC + c;
            k_gin_a<<<GIN_BLOCKS, 256, 0, stream>>>(
                xw, adj, rowptr, clist + c * NN, ccount + c,
                W1 + (size_t)tc * 4096, b1 + (size_t)tc * 64, h1buf,
                bnacc + (size_t)tc * NSHADOW * 128);
            k_gin_c<<<GIN_BLOCKS, 256, 0, stream>>>(
                xw, clist + c * NN, ccount + c,
                g1 + (size_t)tc * 64, be1 + (size_t)tc * 64,
                W2 + (size_t)tc * 4096, b2 + (size_t)tc * 64, h1buf,
                bnacc + (size_t)tc * NSHADOW * 128);
        }
        int pool_waves = (NN + 63) / 64;
        int pool_blocks = (pool_waves * 64 + 255) / 256;
        k_pool<<<pool_blocks, 256, 0, stream>>>(xw, batch, z, t);
    }
    k_final1<<<GG, 256, 0, stream>>>(z, Wp1, bp1, hbuf);
    k_final2<<<1, 256, 0, stream>>>(hbuf, gp, bep, Wp2, bp2, out);
}